// Round 8
// baseline (489.334 us; speedup 1.0000x reference)
//
#include <hip/hip_runtime.h>
#include <stdint.h>

#define D_IN  128
#define D_OUT 64
#define BN_EPS 1e-3f

#define BIN_SHIFT 6
#define BIN_NODES 64           // 1 << BIN_SHIFT
#define BIN_CAP   2560         // avg 2048 records/bin, +11 sigma headroom
#define CHUNK     8192         // edges per partition block (391 blocks)
#define MAX_BINS  1600
#define PT_STRIDE 72           // ushorts: gemm epilogue LDS row stride
#define NQ    4                // src quarters (3.2 MB pre16 slab fits 4 MB XCD L2)
#define NKEY  256              // NQ * BIN_NODES sort keys

typedef __attribute__((ext_vector_type(8))) short bf16x8;
typedef __attribute__((ext_vector_type(4))) float f32x4;

__device__ __forceinline__ ushort f32_to_bf16_rne(float f) {
  uint u = __float_as_uint(f);
  u += 0x7FFFu + ((u >> 16) & 1u);
  return (ushort)(u >> 16);
}
__device__ __forceinline__ float bf16_to_f32(ushort h) {
  return __uint_as_float((uint)h << 16);
}

// ------------- GEMM via MFMA: pre16 = bf16(X @ W), bf16 in / fp32 acc -------
// Row-major pre16[row][64ch]: one node = one 128-B cache line (load-bearing
// for the gather; slab layouts over-fetch 4x on random access — round 1).
// Epilogue stages rows through LDS -> full 128-B line stores. Block 0 zeroes
// bin_cursor and stats (replaces memset dispatches).
__global__ __launch_bounds__(256) void gemm_mfma_kernel(
    const float* __restrict__ x, const float* __restrict__ W,
    ushort* __restrict__ pre16, int* __restrict__ bin_cursor,
    float* __restrict__ stats, int n_bins, int n_nodes, int n_tiles) {
  __shared__ ushort Wb[D_IN * D_OUT];          // 16 KB bf16 copy of W
  __shared__ ushort ptile[64 * PT_STRIDE];     // 9 KB epilogue staging
  const int t = threadIdx.x;
  if (blockIdx.x == 0) {
    for (int i = t; i < n_bins; i += 256) bin_cursor[i] = 0;
    if (t < 128) stats[t] = 0.f;
  }
  for (int i = t; i < D_IN * D_OUT; i += 256) Wb[i] = f32_to_bf16_rne(W[i]);
  __syncthreads();

  const int lane = t & 63;
  const int wave = t >> 6;
  const int m = lane & 15;
  const int quad = lane >> 4;

  bf16x8 bfrag[4][4];
#pragma unroll
  for (int nt = 0; nt < 4; ++nt)
#pragma unroll
    for (int s = 0; s < 4; ++s)
#pragma unroll
      for (int j = 0; j < 8; ++j)
        bfrag[nt][s][j] =
            (short)Wb[(32 * s + quad * 8 + j) * D_OUT + nt * 16 + m];

  for (int tile = blockIdx.x; tile < n_tiles; tile += gridDim.x) {
    const int rbase0 = tile * 64;
    const int row = rbase0 + wave * 16 + m;
    const size_t rl = (size_t)min(row, n_nodes - 1);
    f32x4 acc0 = {0.f, 0.f, 0.f, 0.f}, acc1 = {0.f, 0.f, 0.f, 0.f};
    f32x4 acc2 = {0.f, 0.f, 0.f, 0.f}, acc3 = {0.f, 0.f, 0.f, 0.f};
#pragma unroll
    for (int s = 0; s < 4; ++s) {
      const float4 xa = *(const float4*)&x[rl * D_IN + s * 32 + quad * 8];
      const float4 xb = *(const float4*)&x[rl * D_IN + s * 32 + quad * 8 + 4];
      bf16x8 af;
      af[0] = (short)f32_to_bf16_rne(xa.x);
      af[1] = (short)f32_to_bf16_rne(xa.y);
      af[2] = (short)f32_to_bf16_rne(xa.z);
      af[3] = (short)f32_to_bf16_rne(xa.w);
      af[4] = (short)f32_to_bf16_rne(xb.x);
      af[5] = (short)f32_to_bf16_rne(xb.y);
      af[6] = (short)f32_to_bf16_rne(xb.z);
      af[7] = (short)f32_to_bf16_rne(xb.w);
      acc0 = __builtin_amdgcn_mfma_f32_16x16x32_bf16(af, bfrag[0][s], acc0, 0, 0, 0);
      acc1 = __builtin_amdgcn_mfma_f32_16x16x32_bf16(af, bfrag[1][s], acc1, 0, 0, 0);
      acc2 = __builtin_amdgcn_mfma_f32_16x16x32_bf16(af, bfrag[2][s], acc2, 0, 0, 0);
      acc3 = __builtin_amdgcn_mfma_f32_16x16x32_bf16(af, bfrag[3][s], acc3, 0, 0, 0);
    }
    __syncthreads();  // previous tile's ptile reads complete
#pragma unroll
    for (int reg = 0; reg < 4; ++reg) {
      const int lr = wave * 16 + quad * 4 + reg;
      ptile[lr * PT_STRIDE + m]      = f32_to_bf16_rne(acc0[reg]);
      ptile[lr * PT_STRIDE + 16 + m] = f32_to_bf16_rne(acc1[reg]);
      ptile[lr * PT_STRIDE + 32 + m] = f32_to_bf16_rne(acc2[reg]);
      ptile[lr * PT_STRIDE + 48 + m] = f32_to_bf16_rne(acc3[reg]);
    }
    __syncthreads();
    // cooperative write-out: 4 threads per row, 32 B each -> 128-B lines
    {
      const int lr = t >> 2;
      const int sg = t & 3;
      const int r = rbase0 + lr;
      if (r < n_nodes) {
        const uint4* pl = (const uint4*)&ptile[lr * PT_STRIDE + sg * 16];
        uint4* po = (uint4*)&pre16[(size_t)r * D_OUT + sg * 16];
        po[0] = pl[0];
        po[1] = pl[1];
      }
    }
  }
}

// ---------------- Partition: bin edges by dst>>6, x4-vectorized loads ---------
// Two-phase chunked (proven): per-block LDS histogram + contiguous
// per-(block,bin) reservations -> records written in runs (~5), avoiding the
// 8x write amplification of random 8-B scatter (r6). Deliberately NOT
// sub-binned by src quarter: that would shred run length to ~2 and reintroduce
// the amplification. record: w0 = (dst_low6 << 17) | src17 ; w1 = fp32 val
__global__ __launch_bounds__(256) void partition_kernel(
    const float* __restrict__ ev, const int* __restrict__ esrc,
    const int* __restrict__ edst, int* __restrict__ bin_cursor,
    uint2* __restrict__ bucket, int n_edges, int n_bins) {
  __shared__ int cnt[MAX_BINS];
  __shared__ int base[MAX_BINS];
  const int t = threadIdx.x;
  const int beg = blockIdx.x * CHUNK;
  const int end = min(beg + CHUNK, n_edges);

  for (int i = t; i < n_bins; i += 256) cnt[i] = 0;
  __syncthreads();

  // phase A: histogram, 4 edges per lane per load (1 KB/wave coalesced)
  for (int i = beg + t * 4; i < end; i += 1024) {
    if (i + 3 < end) {
      const int4 d4 = *(const int4*)&edst[i];
      atomicAdd(&cnt[d4.x >> BIN_SHIFT], 1);
      atomicAdd(&cnt[d4.y >> BIN_SHIFT], 1);
      atomicAdd(&cnt[d4.z >> BIN_SHIFT], 1);
      atomicAdd(&cnt[d4.w >> BIN_SHIFT], 1);
    } else {
      for (int k = i; k < end; ++k) atomicAdd(&cnt[edst[k] >> BIN_SHIFT], 1);
    }
  }
  __syncthreads();

  // phase B: reserve contiguous space per (block, bin)
  for (int i = t; i < n_bins; i += 256) {
    const int c = cnt[i];
    int b = 0;
    if (c > 0) b = atomicAdd(&bin_cursor[i], c);
    if (b > BIN_CAP) b = BIN_CAP;
    base[i] = i * BIN_CAP + b;
    cnt[i] = 0;  // reuse as rank cursor
  }
  __syncthreads();

  // phase C: scatter records (re-reads are L2-hot from phase A)
  for (int i = beg + t * 4; i < end; i += 1024) {
    if (i + 3 < end) {
      const int4 d4 = *(const int4*)&edst[i];
      const int4 s4 = *(const int4*)&esrc[i];
      const float4 v4 = *(const float4*)&ev[i];
#pragma unroll
      for (int k = 0; k < 4; ++k) {
        const int dst = (&d4.x)[k];
        const int src = (&s4.x)[k];
        const float v = (&v4.x)[k];
        const int bin = dst >> BIN_SHIFT;
        const int r = atomicAdd(&cnt[bin], 1);
        const int pos = base[bin] + r;
        if (pos < (bin + 1) * BIN_CAP) {
          const uint w0 = ((uint)(dst & (BIN_NODES - 1)) << 17) | (uint)src;
          bucket[pos] = make_uint2(w0, __float_as_uint(v));
        }
      }
    } else {
      for (int k = i; k < end; ++k) {
        const int dst = edst[k];
        const int bin = dst >> BIN_SHIFT;
        const int r = atomicAdd(&cnt[bin], 1);
        const int pos = base[bin] + r;
        if (pos < (bin + 1) * BIN_CAP) {
          const uint w0 = ((uint)(dst & (BIN_NODES - 1)) << 17) | (uint)esrc[k];
          bucket[pos] = make_uint2(w0, __float_as_uint(ev[k]));
        }
      }
    }
  }
}

// ------- Bin sort+gather: src-quartered counting sort for L2 residency -------
// FETCH_SIZE is L2-miss traffic (TCC = per-XCD L2): r7's 157 MB = 26 MB bucket
// + ~130 MB random pre16 misses (12.8 MB working set vs 4 MB XCD L2, ~30% hit),
// served at ~2 TB/s -> the 95-us floor. Fix: sort each bin's records by
// key = src_quarter*64 + node (256 keys) and process quarters SEQUENTIALLY.
// During quarter q every resident block reads only a 3.2-MB pre16 slab, which
// fits each XCD's L2 -> hit rate ~70%+. 256-thread blocks keep all 1563 blocks
// co-resident so quarters stay chip-wide aligned; per-node partial sums
// persist in statically-indexed registers across quarters (rule #20: full
// unroll keeps them out of scratch). Rows stay 128 B: no r1-style over-fetch.
__global__ __launch_bounds__(256) void bin_sort_gather_kernel(
    const ushort* __restrict__ pre16, const uint2* __restrict__ bucket,
    const int* __restrict__ bin_cursor, float* __restrict__ out,
    float* __restrict__ stats, int n_nodes, uint qmagic) {
  __shared__ uint s_src[BIN_CAP];          // 10.0 KB
  __shared__ ushort s_val[BIN_CAP];        // 5.0 KB
  __shared__ int s_hist[NKEY];             // 1 KB
  __shared__ int s_off[NKEY + 1];
  __shared__ int s_cur[NKEY];
  __shared__ float red[4 * 64];
  __shared__ float red2[4 * 64];

  const int t = threadIdx.x;
  const int bin = blockIdx.x;
  const int cnt = min(bin_cursor[bin], BIN_CAP);
  const int64_t rbase = (int64_t)bin * BIN_CAP;

  s_hist[t] = 0;  // t = 0..255 covers NKEY exactly
  __syncthreads();

  for (int i = t; i < cnt; i += 256) {
    const uint w0 = bucket[rbase + i].x;
    const uint src = w0 & 0x1FFFFu;
    const uint q = (uint)(((uint64_t)src * qmagic) >> 35);  // exact src/q_size
    atomicAdd(&s_hist[(int)(q * BIN_NODES + (w0 >> 17))], 1);
  }
  __syncthreads();

  const int own = s_hist[t];
  for (int off = 1; off < NKEY; off <<= 1) {
    const int u = (t >= off) ? s_hist[t - off] : 0;
    __syncthreads();
    s_hist[t] += u;
    __syncthreads();
  }
  s_off[t] = s_hist[t] - own;
  s_cur[t] = s_hist[t] - own;
  if (t == 0) s_off[NKEY] = cnt;
  __syncthreads();

  for (int i = t; i < cnt; i += 256) {
    const uint2 r = bucket[rbase + i];
    const uint src = r.x & 0x1FFFFu;
    const uint q = (uint)(((uint64_t)src * qmagic) >> 35);
    const int p = atomicAdd(&s_cur[(int)(q * BIN_NODES + (r.x >> 17))], 1);
    s_src[p] = src;
    s_val[p] = f32_to_bf16_rne(__uint_as_float(r.y));
  }
  __syncthreads();

  // gather: 4 waves; wave handles 16 node-slots (nl = wave + slot*4);
  // half-waves on even/odd records, 4 loads in flight per half. Per
  // (node, quarter) segment avg 8 records.
  const int lane = t & 63;
  const int wave = t >> 6;
  const int half = lane >> 5;
  const int hl = lane & 31;
  const int node0 = bin * BIN_NODES;

  float accx[16], accy[16];
#pragma unroll
  for (int s = 0; s < 16; ++s) { accx[s] = 0.f; accy[s] = 0.f; }

  for (int q = 0; q < NQ; ++q) {
    const int kb = q * BIN_NODES;
#pragma unroll
    for (int s = 0; s < 16; ++s) {
      const int nl = wave + s * 4;
      const int jb = s_off[kb + nl], je = s_off[kb + nl + 1];
      float a0x = 0.f, a0y = 0.f, a1x = 0.f, a1y = 0.f;
      float a2x = 0.f, a2y = 0.f, a3x = 0.f, a3y = 0.f;
      int j = jb + half;
      for (; j + 6 < je; j += 8) {
        const uint src0 = s_src[j],     src1 = s_src[j + 2];
        const uint src2 = s_src[j + 4], src3 = s_src[j + 6];
        const float v0 = bf16_to_f32(s_val[j]);
        const float v1 = bf16_to_f32(s_val[j + 2]);
        const float v2 = bf16_to_f32(s_val[j + 4]);
        const float v3 = bf16_to_f32(s_val[j + 6]);
        const uint p0 = *(const uint*)&pre16[(size_t)src0 * D_OUT + 2 * hl];
        const uint p1 = *(const uint*)&pre16[(size_t)src1 * D_OUT + 2 * hl];
        const uint p2 = *(const uint*)&pre16[(size_t)src2 * D_OUT + 2 * hl];
        const uint p3 = *(const uint*)&pre16[(size_t)src3 * D_OUT + 2 * hl];
        a0x += v0 * bf16_to_f32((ushort)(p0 & 0xFFFFu));
        a0y += v0 * bf16_to_f32((ushort)(p0 >> 16));
        a1x += v1 * bf16_to_f32((ushort)(p1 & 0xFFFFu));
        a1y += v1 * bf16_to_f32((ushort)(p1 >> 16));
        a2x += v2 * bf16_to_f32((ushort)(p2 & 0xFFFFu));
        a2y += v2 * bf16_to_f32((ushort)(p2 >> 16));
        a3x += v3 * bf16_to_f32((ushort)(p3 & 0xFFFFu));
        a3y += v3 * bf16_to_f32((ushort)(p3 >> 16));
      }
      for (; j < je; j += 2) {
        const uint src = s_src[j];
        const float v = bf16_to_f32(s_val[j]);
        const uint p = *(const uint*)&pre16[(size_t)src * D_OUT + 2 * hl];
        a0x += v * bf16_to_f32((ushort)(p & 0xFFFFu));
        a0y += v * bf16_to_f32((ushort)(p >> 16));
      }
      accx[s] += (a0x + a1x) + (a2x + a3x);
      accy[s] += (a0y + a1y) + (a2y + a3y);
    }
    __syncthreads();  // keep waves quarter-locked (L2 slab residency)
  }

  // epilogue: merge halves, write out rows, block stats
  float csx = 0.f, csy = 0.f, cs2x = 0.f, cs2y = 0.f;
#pragma unroll
  for (int s = 0; s < 16; ++s) {
    const int node = node0 + wave + s * 4;
    float ax = accx[s], ay = accy[s];
    ax += __shfl_xor(ax, 32);
    ay += __shfl_xor(ay, 32);
    if (half == 0 && node < n_nodes) {
      *(float2*)&out[(size_t)node * D_OUT + 2 * hl] = make_float2(ax, ay);
      csx += ax;
      cs2x += ax * ax;
      csy += ay;
      cs2y += ay * ay;
    }
  }
  if (half == 0) {
    red[wave * 64 + 2 * hl] = csx;
    red[wave * 64 + 2 * hl + 1] = csy;
    red2[wave * 64 + 2 * hl] = cs2x;
    red2[wave * 64 + 2 * hl + 1] = cs2y;
  }
  __syncthreads();
  if (t < 64) {
    const float s = red[t] + red[64 + t] + red[128 + t] + red[192 + t];
    const float s2 = red2[t] + red2[64 + t] + red2[128 + t] + red2[192 + t];
    atomicAdd(&stats[t], s);
    atomicAdd(&stats[64 + t], s2);
  }
}

// ---------------- Normalize + ReLU (in place, float4) ----------------
__global__ __launch_bounds__(256) void norm_kernel(
    float* __restrict__ out, const float* __restrict__ stats, int64_t n_vec4,
    float inv_n) {
  const int c = (threadIdx.x * 4) & 63;
  float mean[4], scale[4];
#pragma unroll
  for (int k = 0; k < 4; ++k) {
    mean[k] = stats[c + k] * inv_n;
    const float var = stats[64 + c + k] * inv_n - mean[k] * mean[k];
    scale[k] = rsqrtf(var + BN_EPS);
  }
  const int64_t stride = (int64_t)gridDim.x * 256;
  for (int64_t i = (int64_t)blockIdx.x * 256 + threadIdx.x; i < n_vec4;
       i += stride) {
    float4 v = ((float4*)out)[i];
    v.x = (v.x - mean[0]) * scale[0];
    v.y = (v.y - mean[1]) * scale[1];
    v.z = (v.z - mean[2]) * scale[2];
    v.w = (v.w - mean[3]) * scale[3];
    v.x = v.x > 0.f ? v.x : 0.f;
    v.y = v.y > 0.f ? v.y : 0.f;
    v.z = v.z > 0.f ? v.z : 0.f;
    v.w = v.w > 0.f ? v.w : 0.f;
    ((float4*)out)[i] = v;
  }
}

// ---------------- launch: 4 dispatches total ----------------
extern "C" void kernel_launch(void* const* d_in, const int* in_sizes, int n_in,
                              void* d_out, int out_size, void* d_ws,
                              size_t ws_size, hipStream_t stream) {
  const float* x = (const float*)d_in[0];
  const float* W = (const float*)d_in[1];
  const float* ev = (const float*)d_in[2];
  const int* esrc = (const int*)d_in[3];
  const int* edst = (const int*)d_in[4];

  const int n_nodes = in_sizes[0] / D_IN;
  const int n_edges = in_sizes[2];
  const int64_t n_out = (int64_t)n_nodes * D_OUT;
  const int n_bins = (n_nodes + BIN_NODES - 1) >> BIN_SHIFT;
  const int n_row_tiles = (n_nodes + 63) / 64;

  // exact floor(src / q_size) via round-up magic: valid for src < 2^17 since
  // delta = M*q_size - 2^35 < q_size << 2^35 / src_max
  const uint q_size = (uint)((n_nodes + NQ - 1) / NQ);
  const uint qmagic = (uint)(((1ull << 35) + q_size - 1) / q_size);

  float* out = (float*)d_out;

  // workspace layout
  char* w = (char*)d_ws;
  ushort* pre16 = (ushort*)w;             w += (size_t)n_nodes * D_OUT * 2;
  int* bin_cursor = (int*)w;              w += (size_t)n_bins * 4;
  float* stats = (float*)w;               w += 128 * 4;
  w = (char*)(((uintptr_t)w + 7) & ~(uintptr_t)7);
  uint2* bucket = (uint2*)w;              // n_bins * BIN_CAP * 8 bytes (~32 MB)

  gemm_mfma_kernel<<<(n_row_tiles + 1) / 2, 256, 0, stream>>>(
      x, W, pre16, bin_cursor, stats, n_bins, n_nodes, n_row_tiles);
  partition_kernel<<<(n_edges + CHUNK - 1) / CHUNK, 256, 0, stream>>>(
      ev, esrc, edst, bin_cursor, bucket, n_edges, n_bins);
  bin_sort_gather_kernel<<<n_bins, 256, 0, stream>>>(
      pre16, bucket, bin_cursor, out, stats, n_nodes, qmagic);
  norm_kernel<<<2048, 256, 0, stream>>>(out, stats, n_out / 4,
                                        1.0f / (float)n_nodes);
}

// Round 9
// 298.933 us; speedup vs baseline: 1.6369x; 1.6369x over previous
//
#include <hip/hip_runtime.h>
#include <stdint.h>

#define D_IN  128
#define D_OUT 64
#define BN_EPS 1e-3f

#define BIN_SHIFT 6
#define BIN_NODES 64           // 1 << BIN_SHIFT
#define BIN_CAP   2560         // avg 2048 records/bin, +11 sigma headroom
#define CHUNK     8192         // edges per partition-role block (391 blocks)
#define MAX_BINS  1600
#define PT_STRIDE 72           // ushorts: gemm epilogue LDS row stride

typedef __attribute__((ext_vector_type(8))) short bf16x8;
typedef __attribute__((ext_vector_type(4))) float f32x4;

__device__ __forceinline__ ushort f32_to_bf16_rne(float f) {
  uint u = __float_as_uint(f);
  u += 0x7FFFu + ((u >> 16) & 1u);
  return (ushort)(u >> 16);
}
__device__ __forceinline__ float bf16_to_f32(ushort h) {
  return __uint_as_float((uint)h << 16);
}

// ------------- Fused GEMM + partition: role-split blocks ---------------------
// gemm (blocks [0, n_gemm)): pre16 = bf16(X @ W) via MFMA, row-major
//   pre16[row][64ch] = one 128-B line per node (load-bearing for gather, r1).
//   Epilogue staged through LDS -> full-line stores.
// partition (blocks [n_gemm, n_gemm+391)): two-phase chunked binning (proven):
//   LDS histogram + contiguous per-(block,bin) reservations -> records written
//   in runs of ~5 (r6: random 8-B scatter = 8x write amplification, 245 us).
// The two roles touch disjoint data (x,W->pre16 vs edges->bucket) and today
// serialize on the stream; fused, gemm's ~20 us hides under partition, and the
// fused duration exposes the partition critical path in the top-5 at last.
// record: w0 = (dst_low6 << 17) | src17 ; w1 = fp32 edge_val
__global__ __launch_bounds__(256) void gemm_partition_kernel(
    const float* __restrict__ x, const float* __restrict__ W,
    const float* __restrict__ ev, const int* __restrict__ esrc,
    const int* __restrict__ edst, ushort* __restrict__ pre16,
    int* __restrict__ bin_cursor, uint2* __restrict__ bucket,
    int n_nodes, int n_tiles, int n_edges, int n_bins, int n_gemm) {
  __shared__ char smem[25600];  // union: gemm Wb(16K)+ptile(9.2K) | part cnt/base(12.8K)
  const int t = threadIdx.x;

  if ((int)blockIdx.x < n_gemm) {
    // ---------------- gemm role ----------------
    ushort* Wb = (ushort*)smem;                    // 16384 B
    ushort* ptile = (ushort*)(smem + 16384);       // 9216 B
    for (int i = t; i < D_IN * D_OUT; i += 256) Wb[i] = f32_to_bf16_rne(W[i]);
    __syncthreads();

    const int lane = t & 63;
    const int wave = t >> 6;
    const int m = lane & 15;
    const int quad = lane >> 4;

    bf16x8 bfrag[4][4];
#pragma unroll
    for (int nt = 0; nt < 4; ++nt)
#pragma unroll
      for (int s = 0; s < 4; ++s)
#pragma unroll
        for (int j = 0; j < 8; ++j)
          bfrag[nt][s][j] =
              (short)Wb[(32 * s + quad * 8 + j) * D_OUT + nt * 16 + m];

    for (int tile = blockIdx.x; tile < n_tiles; tile += n_gemm) {
      const int rbase0 = tile * 64;
      const int row = rbase0 + wave * 16 + m;
      const size_t rl = (size_t)min(row, n_nodes - 1);
      f32x4 acc0 = {0.f, 0.f, 0.f, 0.f}, acc1 = {0.f, 0.f, 0.f, 0.f};
      f32x4 acc2 = {0.f, 0.f, 0.f, 0.f}, acc3 = {0.f, 0.f, 0.f, 0.f};
#pragma unroll
      for (int s = 0; s < 4; ++s) {
        const float4 xa = *(const float4*)&x[rl * D_IN + s * 32 + quad * 8];
        const float4 xb = *(const float4*)&x[rl * D_IN + s * 32 + quad * 8 + 4];
        bf16x8 af;
        af[0] = (short)f32_to_bf16_rne(xa.x);
        af[1] = (short)f32_to_bf16_rne(xa.y);
        af[2] = (short)f32_to_bf16_rne(xa.z);
        af[3] = (short)f32_to_bf16_rne(xa.w);
        af[4] = (short)f32_to_bf16_rne(xb.x);
        af[5] = (short)f32_to_bf16_rne(xb.y);
        af[6] = (short)f32_to_bf16_rne(xb.z);
        af[7] = (short)f32_to_bf16_rne(xb.w);
        acc0 = __builtin_amdgcn_mfma_f32_16x16x32_bf16(af, bfrag[0][s], acc0, 0, 0, 0);
        acc1 = __builtin_amdgcn_mfma_f32_16x16x32_bf16(af, bfrag[1][s], acc1, 0, 0, 0);
        acc2 = __builtin_amdgcn_mfma_f32_16x16x32_bf16(af, bfrag[2][s], acc2, 0, 0, 0);
        acc3 = __builtin_amdgcn_mfma_f32_16x16x32_bf16(af, bfrag[3][s], acc3, 0, 0, 0);
      }
      __syncthreads();  // previous tile's ptile reads complete
#pragma unroll
      for (int reg = 0; reg < 4; ++reg) {
        const int lr = wave * 16 + quad * 4 + reg;
        ptile[lr * PT_STRIDE + m]      = f32_to_bf16_rne(acc0[reg]);
        ptile[lr * PT_STRIDE + 16 + m] = f32_to_bf16_rne(acc1[reg]);
        ptile[lr * PT_STRIDE + 32 + m] = f32_to_bf16_rne(acc2[reg]);
        ptile[lr * PT_STRIDE + 48 + m] = f32_to_bf16_rne(acc3[reg]);
      }
      __syncthreads();
      // cooperative write-out: 4 threads per row, 32 B each -> 128-B lines
      {
        const int lr = t >> 2;
        const int sg = t & 3;
        const int r = rbase0 + lr;
        if (r < n_nodes) {
          const uint4* pl = (const uint4*)&ptile[lr * PT_STRIDE + sg * 16];
          uint4* po = (uint4*)&pre16[(size_t)r * D_OUT + sg * 16];
          po[0] = pl[0];
          po[1] = pl[1];
        }
      }
    }
  } else {
    // ---------------- partition role ----------------
    int* cnt = (int*)smem;                         // MAX_BINS*4
    int* base = (int*)(smem + MAX_BINS * 4);       // MAX_BINS*4
    const int bp = (int)blockIdx.x - n_gemm;
    const int beg = bp * CHUNK;
    const int end = min(beg + CHUNK, n_edges);

    for (int i = t; i < n_bins; i += 256) cnt[i] = 0;
    __syncthreads();

    // phase A: histogram, 4 edges per lane per load (1 KB/wave coalesced)
    for (int i = beg + t * 4; i < end; i += 1024) {
      if (i + 3 < end) {
        const int4 d4 = *(const int4*)&edst[i];
        atomicAdd(&cnt[d4.x >> BIN_SHIFT], 1);
        atomicAdd(&cnt[d4.y >> BIN_SHIFT], 1);
        atomicAdd(&cnt[d4.z >> BIN_SHIFT], 1);
        atomicAdd(&cnt[d4.w >> BIN_SHIFT], 1);
      } else {
        for (int k = i; k < end; ++k) atomicAdd(&cnt[edst[k] >> BIN_SHIFT], 1);
      }
    }
    __syncthreads();

    // phase B: reserve contiguous space per (block, bin)
    for (int i = t; i < n_bins; i += 256) {
      const int c = cnt[i];
      int b = 0;
      if (c > 0) b = atomicAdd(&bin_cursor[i], c);
      if (b > BIN_CAP) b = BIN_CAP;
      base[i] = i * BIN_CAP + b;
      cnt[i] = 0;  // reuse as rank cursor
    }
    __syncthreads();

    // phase C: scatter records (re-reads are L1/L2-hot from phase A)
    for (int i = beg + t * 4; i < end; i += 1024) {
      if (i + 3 < end) {
        const int4 d4 = *(const int4*)&edst[i];
        const int4 s4 = *(const int4*)&esrc[i];
        const float4 v4 = *(const float4*)&ev[i];
#pragma unroll
        for (int k = 0; k < 4; ++k) {
          const int dst = (&d4.x)[k];
          const int src = (&s4.x)[k];
          const float v = (&v4.x)[k];
          const int bin = dst >> BIN_SHIFT;
          const int r = atomicAdd(&cnt[bin], 1);
          const int pos = base[bin] + r;
          if (pos < (bin + 1) * BIN_CAP) {
            const uint w0 = ((uint)(dst & (BIN_NODES - 1)) << 17) | (uint)src;
            bucket[pos] = make_uint2(w0, __float_as_uint(v));
          }
        }
      } else {
        for (int k = i; k < end; ++k) {
          const int dst = edst[k];
          const int bin = dst >> BIN_SHIFT;
          const int r = atomicAdd(&cnt[bin], 1);
          const int pos = base[bin] + r;
          if (pos < (bin + 1) * BIN_CAP) {
            const uint w0 = ((uint)(dst & (BIN_NODES - 1)) << 17) | (uint)esrc[k];
            bucket[pos] = make_uint2(w0, __float_as_uint(ev[k]));
          }
        }
      }
    }
  }
}

// ------- Bin sort+gather: LDS counting sort, half-wave gather (r7, proven) ---
// 512 threads / 8 waves, 95-96 us. Near the random-line concurrency wall:
// 1.28M line misses x ~700 ns / ~10K outstanding ~= 90 us. r8's quarter-
// slicing cut FETCH 157->125 MB but fragmented segments 4x -> tail-dominated,
// VGPR 96, occupancy 17.5%, 288 us. Do not re-fragment this loop.
__global__ __launch_bounds__(512) void bin_sort_gather_kernel(
    const ushort* __restrict__ pre16, const uint2* __restrict__ bucket,
    const int* __restrict__ bin_cursor, float* __restrict__ out,
    float* __restrict__ stats, int n_nodes) {
  __shared__ uint s_src[BIN_CAP];          // 10.0 KB
  __shared__ ushort s_val[BIN_CAP];        // 5.0 KB
  __shared__ int s_hist[BIN_NODES];
  __shared__ int s_off[BIN_NODES + 1];
  __shared__ int s_cur[BIN_NODES];

  const int t = threadIdx.x;
  const int bin = blockIdx.x;
  const int cnt = min(bin_cursor[bin], BIN_CAP);
  const int64_t rbase = (int64_t)bin * BIN_CAP;

  if (t < BIN_NODES) s_hist[t] = 0;
  __syncthreads();

  for (int i = t; i < cnt; i += 512)
    atomicAdd(&s_hist[bucket[rbase + i].x >> 17], 1);
  __syncthreads();

  int own = (t < BIN_NODES) ? s_hist[t] : 0;
  for (int off = 1; off < BIN_NODES; off <<= 1) {
    int u = 0;
    if (t < BIN_NODES && t >= off) u = s_hist[t - off];
    __syncthreads();
    if (t < BIN_NODES) s_hist[t] += u;
    __syncthreads();
  }
  if (t < BIN_NODES) {
    const int e = s_hist[t] - own;
    s_off[t] = e;
    s_cur[t] = e;
  }
  if (t == 0) s_off[BIN_NODES] = cnt;
  __syncthreads();

  for (int i = t; i < cnt; i += 512) {
    const uint2 r = bucket[rbase + i];
    const int d = r.x >> 17;
    const int p = atomicAdd(&s_cur[d], 1);
    s_src[p] = r.x & 0x1FFFFu;
    s_val[p] = f32_to_bf16_rne(__uint_as_float(r.y));
  }
  __syncthreads();

  // gather: wave per node (8 waves -> 8 nodes in flight); half-waves on
  // even/odd records; 8 records/half in flight in the main loop.
  const int lane = t & 63;
  const int wave = t >> 6;
  const int half = lane >> 5;
  const int hl = lane & 31;
  const int node0 = bin * BIN_NODES;
  float csx = 0.f, csy = 0.f, cs2x = 0.f, cs2y = 0.f;

  for (int nl = wave; nl < BIN_NODES; nl += 8) {
    const int node = node0 + nl;
    if (node < n_nodes) {
      const int jb = s_off[nl], je = s_off[nl + 1];
      float a0x = 0.f, a0y = 0.f, a1x = 0.f, a1y = 0.f;
      float a2x = 0.f, a2y = 0.f, a3x = 0.f, a3y = 0.f;
      float a4x = 0.f, a4y = 0.f, a5x = 0.f, a5y = 0.f;
      float a6x = 0.f, a6y = 0.f, a7x = 0.f, a7y = 0.f;
      int j = jb + half;
      // main: 16 records per wave-iteration, 8 loads in flight per half
      for (; j + 14 < je; j += 16) {
        const uint src0 = s_src[j],      src1 = s_src[j + 2];
        const uint src2 = s_src[j + 4],  src3 = s_src[j + 6];
        const uint src4 = s_src[j + 8],  src5 = s_src[j + 10];
        const uint src6 = s_src[j + 12], src7 = s_src[j + 14];
        const float v0 = bf16_to_f32(s_val[j]);
        const float v1 = bf16_to_f32(s_val[j + 2]);
        const float v2 = bf16_to_f32(s_val[j + 4]);
        const float v3 = bf16_to_f32(s_val[j + 6]);
        const float v4 = bf16_to_f32(s_val[j + 8]);
        const float v5 = bf16_to_f32(s_val[j + 10]);
        const float v6 = bf16_to_f32(s_val[j + 12]);
        const float v7 = bf16_to_f32(s_val[j + 14]);
        const uint p0 = *(const uint*)&pre16[(size_t)src0 * D_OUT + 2 * hl];
        const uint p1 = *(const uint*)&pre16[(size_t)src1 * D_OUT + 2 * hl];
        const uint p2 = *(const uint*)&pre16[(size_t)src2 * D_OUT + 2 * hl];
        const uint p3 = *(const uint*)&pre16[(size_t)src3 * D_OUT + 2 * hl];
        const uint p4 = *(const uint*)&pre16[(size_t)src4 * D_OUT + 2 * hl];
        const uint p5 = *(const uint*)&pre16[(size_t)src5 * D_OUT + 2 * hl];
        const uint p6 = *(const uint*)&pre16[(size_t)src6 * D_OUT + 2 * hl];
        const uint p7 = *(const uint*)&pre16[(size_t)src7 * D_OUT + 2 * hl];
        a0x += v0 * bf16_to_f32((ushort)(p0 & 0xFFFFu));
        a0y += v0 * bf16_to_f32((ushort)(p0 >> 16));
        a1x += v1 * bf16_to_f32((ushort)(p1 & 0xFFFFu));
        a1y += v1 * bf16_to_f32((ushort)(p1 >> 16));
        a2x += v2 * bf16_to_f32((ushort)(p2 & 0xFFFFu));
        a2y += v2 * bf16_to_f32((ushort)(p2 >> 16));
        a3x += v3 * bf16_to_f32((ushort)(p3 & 0xFFFFu));
        a3y += v3 * bf16_to_f32((ushort)(p3 >> 16));
        a4x += v4 * bf16_to_f32((ushort)(p4 & 0xFFFFu));
        a4y += v4 * bf16_to_f32((ushort)(p4 >> 16));
        a5x += v5 * bf16_to_f32((ushort)(p5 & 0xFFFFu));
        a5y += v5 * bf16_to_f32((ushort)(p5 >> 16));
        a6x += v6 * bf16_to_f32((ushort)(p6 & 0xFFFFu));
        a6y += v6 * bf16_to_f32((ushort)(p6 >> 16));
        a7x += v7 * bf16_to_f32((ushort)(p7 & 0xFFFFu));
        a7y += v7 * bf16_to_f32((ushort)(p7 >> 16));
      }
      // mid: 8 records per wave-iteration, 4 loads in flight per half
      for (; j + 6 < je; j += 8) {
        const uint src0 = s_src[j],     src1 = s_src[j + 2];
        const uint src2 = s_src[j + 4], src3 = s_src[j + 6];
        const float v0 = bf16_to_f32(s_val[j]);
        const float v1 = bf16_to_f32(s_val[j + 2]);
        const float v2 = bf16_to_f32(s_val[j + 4]);
        const float v3 = bf16_to_f32(s_val[j + 6]);
        const uint p0 = *(const uint*)&pre16[(size_t)src0 * D_OUT + 2 * hl];
        const uint p1 = *(const uint*)&pre16[(size_t)src1 * D_OUT + 2 * hl];
        const uint p2 = *(const uint*)&pre16[(size_t)src2 * D_OUT + 2 * hl];
        const uint p3 = *(const uint*)&pre16[(size_t)src3 * D_OUT + 2 * hl];
        a0x += v0 * bf16_to_f32((ushort)(p0 & 0xFFFFu));
        a0y += v0 * bf16_to_f32((ushort)(p0 >> 16));
        a1x += v1 * bf16_to_f32((ushort)(p1 & 0xFFFFu));
        a1y += v1 * bf16_to_f32((ushort)(p1 >> 16));
        a2x += v2 * bf16_to_f32((ushort)(p2 & 0xFFFFu));
        a2y += v2 * bf16_to_f32((ushort)(p2 >> 16));
        a3x += v3 * bf16_to_f32((ushort)(p3 & 0xFFFFu));
        a3y += v3 * bf16_to_f32((ushort)(p3 >> 16));
      }
      for (; j < je; j += 2) {
        const uint src = s_src[j];
        const float v = bf16_to_f32(s_val[j]);
        const uint p = *(const uint*)&pre16[(size_t)src * D_OUT + 2 * hl];
        a0x += v * bf16_to_f32((ushort)(p & 0xFFFFu));
        a0y += v * bf16_to_f32((ushort)(p >> 16));
      }
      float ax = ((a0x + a1x) + (a2x + a3x)) + ((a4x + a5x) + (a6x + a7x));
      float ay = ((a0y + a1y) + (a2y + a3y)) + ((a4y + a5y) + (a6y + a7y));
      ax += __shfl_xor(ax, 32);   // merge odd-record half into even half
      ay += __shfl_xor(ay, 32);
      if (half == 0) {
        *(float2*)&out[(size_t)node * D_OUT + 2 * hl] = make_float2(ax, ay);
        csx += ax;
        cs2x += ax * ax;
        csy += ay;
        cs2y += ay * ay;
      }
    }
  }
  __syncthreads();  // record reads done; alias reduction buffers onto s_src

  float* red = (float*)s_src;       // [8 waves][64 cols] sums (2 KB)
  float* red2 = red + 512;          // [8 waves][64 cols] sumsq (2 KB)
  if (half == 0) {
    red[wave * 64 + 2 * hl] = csx;
    red[wave * 64 + 2 * hl + 1] = csy;
    red2[wave * 64 + 2 * hl] = cs2x;
    red2[wave * 64 + 2 * hl + 1] = cs2y;
  }
  __syncthreads();
  if (t < 64) {
    float s = 0.f, s2 = 0.f;
#pragma unroll
    for (int wv = 0; wv < 8; ++wv) {
      s += red[wv * 64 + t];
      s2 += red2[wv * 64 + t];
    }
    atomicAdd(&stats[t], s);
    atomicAdd(&stats[64 + t], s2);
  }
}

// ---------------- Normalize + ReLU (in place, float4) ----------------
__global__ __launch_bounds__(256) void norm_kernel(
    float* __restrict__ out, const float* __restrict__ stats, int64_t n_vec4,
    float inv_n) {
  const int c = (threadIdx.x * 4) & 63;
  float mean[4], scale[4];
#pragma unroll
  for (int k = 0; k < 4; ++k) {
    mean[k] = stats[c + k] * inv_n;
    const float var = stats[64 + c + k] * inv_n - mean[k] * mean[k];
    scale[k] = rsqrtf(var + BN_EPS);
  }
  const int64_t stride = (int64_t)gridDim.x * 256;
  for (int64_t i = (int64_t)blockIdx.x * 256 + threadIdx.x; i < n_vec4;
       i += stride) {
    float4 v = ((float4*)out)[i];
    v.x = (v.x - mean[0]) * scale[0];
    v.y = (v.y - mean[1]) * scale[1];
    v.z = (v.z - mean[2]) * scale[2];
    v.w = (v.w - mean[3]) * scale[3];
    v.x = v.x > 0.f ? v.x : 0.f;
    v.y = v.y > 0.f ? v.y : 0.f;
    v.z = v.z > 0.f ? v.z : 0.f;
    v.w = v.w > 0.f ? v.w : 0.f;
    ((float4*)out)[i] = v;
  }
}

// ---------------- launch: memset + 3 kernel dispatches ----------------
extern "C" void kernel_launch(void* const* d_in, const int* in_sizes, int n_in,
                              void* d_out, int out_size, void* d_ws,
                              size_t ws_size, hipStream_t stream) {
  const float* x = (const float*)d_in[0];
  const float* W = (const float*)d_in[1];
  const float* ev = (const float*)d_in[2];
  const int* esrc = (const int*)d_in[3];
  const int* edst = (const int*)d_in[4];

  const int n_nodes = in_sizes[0] / D_IN;
  const int n_edges = in_sizes[2];
  const int64_t n_out = (int64_t)n_nodes * D_OUT;
  const int n_bins = (n_nodes + BIN_NODES - 1) >> BIN_SHIFT;
  const int n_row_tiles = (n_nodes + 63) / 64;
  const int n_gemm = (n_row_tiles + 1) / 2;
  const int n_part = (n_edges + CHUNK - 1) / CHUNK;

  float* out = (float*)d_out;

  // workspace layout (bin_cursor and stats adjacent: one memset covers both)
  char* w = (char*)d_ws;
  ushort* pre16 = (ushort*)w;             w += (size_t)n_nodes * D_OUT * 2;
  int* bin_cursor = (int*)w;              w += (size_t)n_bins * 4;
  float* stats = (float*)w;               w += 128 * 4;
  w = (char*)(((uintptr_t)w + 7) & ~(uintptr_t)7);
  uint2* bucket = (uint2*)w;              // n_bins * BIN_CAP * 8 bytes (~32 MB)

  hipMemsetAsync(bin_cursor, 0, (size_t)n_bins * 4 + 128 * 4, stream);
  gemm_partition_kernel<<<n_gemm + n_part, 256, 0, stream>>>(
      x, W, ev, esrc, edst, pre16, bin_cursor, bucket, n_nodes, n_row_tiles,
      n_edges, n_bins, n_gemm);
  bin_sort_gather_kernel<<<n_bins, 512, 0, stream>>>(pre16, bucket, bin_cursor,
                                                     out, stats, n_nodes);
  norm_kernel<<<2048, 256, 0, stream>>>(out, stats, n_out / 4,
                                        1.0f / (float)n_nodes);
}

// Round 10
// 292.621 us; speedup vs baseline: 1.6722x; 1.0216x over previous
//
#include <hip/hip_runtime.h>
#include <stdint.h>

#define D_IN  128
#define D_OUT 64
#define BN_EPS 1e-3f

#define BIN_SHIFT 7
#define BIN_NODES 128          // 1 << BIN_SHIFT
#define BIN_CAP   5120         // avg 4096 records/bin, +16 sigma headroom
#define CHUNK     8192         // edges per partition block (391 blocks)
#define MAX_BINS  800
#define PT_STRIDE 72           // ushorts: gemm epilogue LDS row stride

typedef __attribute__((ext_vector_type(8))) short bf16x8;
typedef __attribute__((ext_vector_type(4))) float f32x4;

__device__ __forceinline__ ushort f32_to_bf16_rne(float f) {
  uint u = __float_as_uint(f);
  u += 0x7FFFu + ((u >> 16) & 1u);
  return (ushort)(u >> 16);
}
__device__ __forceinline__ float bf16_to_f32(ushort h) {
  return __uint_as_float((uint)h << 16);
}

// ------------- GEMM via MFMA: pre16 = bf16(X @ W), bf16 in / fp32 acc -------
// Row-major pre16[row][64ch]: one node = one 128-B cache line (load-bearing
// for the gather; r1: slab layouts over-fetch 4x on random access).
// Epilogue staged through LDS -> full 128-B line stores. Block 0 zeroes
// bin_cursor+stats (replaces memset dispatches; safe: stream order puts all
// of gemm before partition).
__global__ __launch_bounds__(256) void gemm_mfma_kernel(
    const float* __restrict__ x, const float* __restrict__ W,
    ushort* __restrict__ pre16, int* __restrict__ bin_cursor,
    float* __restrict__ stats, int n_bins, int n_nodes, int n_tiles) {
  __shared__ ushort Wb[D_IN * D_OUT];          // 16 KB bf16 copy of W
  __shared__ ushort ptile[64 * PT_STRIDE];     // 9 KB epilogue staging
  const int t = threadIdx.x;
  if (blockIdx.x == 0) {
    for (int i = t; i < n_bins; i += 256) bin_cursor[i] = 0;
    if (t < 128) stats[t] = 0.f;
  }
  for (int i = t; i < D_IN * D_OUT; i += 256) Wb[i] = f32_to_bf16_rne(W[i]);
  __syncthreads();

  const int lane = t & 63;
  const int wave = t >> 6;
  const int m = lane & 15;
  const int quad = lane >> 4;

  bf16x8 bfrag[4][4];
#pragma unroll
  for (int nt = 0; nt < 4; ++nt)
#pragma unroll
    for (int s = 0; s < 4; ++s)
#pragma unroll
      for (int j = 0; j < 8; ++j)
        bfrag[nt][s][j] =
            (short)Wb[(32 * s + quad * 8 + j) * D_OUT + nt * 16 + m];

  for (int tile = blockIdx.x; tile < n_tiles; tile += gridDim.x) {
    const int rbase0 = tile * 64;
    const int row = rbase0 + wave * 16 + m;
    const size_t rl = (size_t)min(row, n_nodes - 1);
    f32x4 acc0 = {0.f, 0.f, 0.f, 0.f}, acc1 = {0.f, 0.f, 0.f, 0.f};
    f32x4 acc2 = {0.f, 0.f, 0.f, 0.f}, acc3 = {0.f, 0.f, 0.f, 0.f};
#pragma unroll
    for (int s = 0; s < 4; ++s) {
      const float4 xa = *(const float4*)&x[rl * D_IN + s * 32 + quad * 8];
      const float4 xb = *(const float4*)&x[rl * D_IN + s * 32 + quad * 8 + 4];
      bf16x8 af;
      af[0] = (short)f32_to_bf16_rne(xa.x);
      af[1] = (short)f32_to_bf16_rne(xa.y);
      af[2] = (short)f32_to_bf16_rne(xa.z);
      af[3] = (short)f32_to_bf16_rne(xa.w);
      af[4] = (short)f32_to_bf16_rne(xb.x);
      af[5] = (short)f32_to_bf16_rne(xb.y);
      af[6] = (short)f32_to_bf16_rne(xb.z);
      af[7] = (short)f32_to_bf16_rne(xb.w);
      acc0 = __builtin_amdgcn_mfma_f32_16x16x32_bf16(af, bfrag[0][s], acc0, 0, 0, 0);
      acc1 = __builtin_amdgcn_mfma_f32_16x16x32_bf16(af, bfrag[1][s], acc1, 0, 0, 0);
      acc2 = __builtin_amdgcn_mfma_f32_16x16x32_bf16(af, bfrag[2][s], acc2, 0, 0, 0);
      acc3 = __builtin_amdgcn_mfma_f32_16x16x32_bf16(af, bfrag[3][s], acc3, 0, 0, 0);
    }
    __syncthreads();  // previous tile's ptile reads complete
#pragma unroll
    for (int reg = 0; reg < 4; ++reg) {
      const int lr = wave * 16 + quad * 4 + reg;
      ptile[lr * PT_STRIDE + m]      = f32_to_bf16_rne(acc0[reg]);
      ptile[lr * PT_STRIDE + 16 + m] = f32_to_bf16_rne(acc1[reg]);
      ptile[lr * PT_STRIDE + 32 + m] = f32_to_bf16_rne(acc2[reg]);
      ptile[lr * PT_STRIDE + 48 + m] = f32_to_bf16_rne(acc3[reg]);
    }
    __syncthreads();
    // cooperative write-out: 4 threads per row, 32 B each -> 128-B lines
    {
      const int lr = t >> 2;
      const int sg = t & 3;
      const int r = rbase0 + lr;
      if (r < n_nodes) {
        const uint4* pl = (const uint4*)&ptile[lr * PT_STRIDE + sg * 16];
        uint4* po = (uint4*)&pre16[(size_t)r * D_OUT + sg * 16];
        po[0] = pl[0];
        po[1] = pl[1];
      }
    }
  }
}

// ---------------- Partition: bin edges by dst>>7, x4-vectorized loads ---------
// Two-phase chunked (proven). r9 diagnosis: with 1563 bins, run length was
// 5.2 records (40 B) -> ~3.2x bucket write amplification (WRITE_SIZE 97 MB vs
// 39 ideal). 782 bins doubles run length to 10.5 (84 B) -> amp ~1.5x,
// saving ~45 MB of HBM writes. record: w0 = (dst_low7 << 17) | src17.
__global__ __launch_bounds__(256) void partition_kernel(
    const float* __restrict__ ev, const int* __restrict__ esrc,
    const int* __restrict__ edst, int* __restrict__ bin_cursor,
    uint2* __restrict__ bucket, int n_edges, int n_bins) {
  __shared__ int cnt[MAX_BINS];
  __shared__ int base[MAX_BINS];
  const int t = threadIdx.x;
  const int beg = blockIdx.x * CHUNK;
  const int end = min(beg + CHUNK, n_edges);

  for (int i = t; i < n_bins; i += 256) cnt[i] = 0;
  __syncthreads();

  // phase A: histogram, 4 edges per lane per load (1 KB/wave coalesced)
  for (int i = beg + t * 4; i < end; i += 1024) {
    if (i + 3 < end) {
      const int4 d4 = *(const int4*)&edst[i];
      atomicAdd(&cnt[d4.x >> BIN_SHIFT], 1);
      atomicAdd(&cnt[d4.y >> BIN_SHIFT], 1);
      atomicAdd(&cnt[d4.z >> BIN_SHIFT], 1);
      atomicAdd(&cnt[d4.w >> BIN_SHIFT], 1);
    } else {
      for (int k = i; k < end; ++k) atomicAdd(&cnt[edst[k] >> BIN_SHIFT], 1);
    }
  }
  __syncthreads();

  // phase B: reserve contiguous space per (block, bin)
  for (int i = t; i < n_bins; i += 256) {
    const int c = cnt[i];
    int b = 0;
    if (c > 0) b = atomicAdd(&bin_cursor[i], c);
    if (b > BIN_CAP) b = BIN_CAP;
    base[i] = i * BIN_CAP + b;
    cnt[i] = 0;  // reuse as rank cursor
  }
  __syncthreads();

  // phase C: scatter records (re-reads are L2-hot from phase A)
  for (int i = beg + t * 4; i < end; i += 1024) {
    if (i + 3 < end) {
      const int4 d4 = *(const int4*)&edst[i];
      const int4 s4 = *(const int4*)&esrc[i];
      const float4 v4 = *(const float4*)&ev[i];
#pragma unroll
      for (int k = 0; k < 4; ++k) {
        const int dst = (&d4.x)[k];
        const int src = (&s4.x)[k];
        const float v = (&v4.x)[k];
        const int bin = dst >> BIN_SHIFT;
        const int r = atomicAdd(&cnt[bin], 1);
        const int pos = base[bin] + r;
        if (pos < (bin + 1) * BIN_CAP) {
          const uint w0 = ((uint)(dst & (BIN_NODES - 1)) << 17) | (uint)src;
          bucket[pos] = make_uint2(w0, __float_as_uint(v));
        }
      }
    } else {
      for (int k = i; k < end; ++k) {
        const int dst = edst[k];
        const int bin = dst >> BIN_SHIFT;
        const int r = atomicAdd(&cnt[bin], 1);
        const int pos = base[bin] + r;
        if (pos < (bin + 1) * BIN_CAP) {
          const uint w0 = ((uint)(dst & (BIN_NODES - 1)) << 17) | (uint)esrc[k];
          bucket[pos] = make_uint2(w0, __float_as_uint(ev[k]));
        }
      }
    }
  }
}

// ------- Bin sort+gather: LDS counting sort, half-wave gather ----------------
// 128 nodes/bin now: s_src 20K + s_val 10K + hist/off/cur 1.5K = 32.3 KB ->
// 4 blocks/CU x 8 waves; with 782 blocks the grid is block-slot-bound at the
// same ~24 waves/CU as before, so gather perf is preserved while partition
// gains. Inner loop untouched (r8 lesson: do not fragment this stream).
// Near the random-line concurrency wall: 1.28M line misses x ~700 ns /
// ~10K outstanding ~= 90 us.
__global__ __launch_bounds__(512) void bin_sort_gather_kernel(
    const ushort* __restrict__ pre16, const uint2* __restrict__ bucket,
    const int* __restrict__ bin_cursor, float* __restrict__ out,
    float* __restrict__ stats, int n_nodes) {
  __shared__ uint s_src[BIN_CAP];          // 20.0 KB
  __shared__ ushort s_val[BIN_CAP];        // 10.0 KB
  __shared__ int s_hist[BIN_NODES];
  __shared__ int s_off[BIN_NODES + 1];
  __shared__ int s_cur[BIN_NODES];

  const int t = threadIdx.x;
  const int bin = blockIdx.x;
  const int cnt = min(bin_cursor[bin], BIN_CAP);
  const int64_t rbase = (int64_t)bin * BIN_CAP;

  if (t < BIN_NODES) s_hist[t] = 0;
  __syncthreads();

  for (int i = t; i < cnt; i += 512)
    atomicAdd(&s_hist[bucket[rbase + i].x >> 17], 1);
  __syncthreads();

  int own = (t < BIN_NODES) ? s_hist[t] : 0;
  for (int off = 1; off < BIN_NODES; off <<= 1) {
    int u = 0;
    if (t < BIN_NODES && t >= off) u = s_hist[t - off];
    __syncthreads();
    if (t < BIN_NODES) s_hist[t] += u;
    __syncthreads();
  }
  if (t < BIN_NODES) {
    const int e = s_hist[t] - own;
    s_off[t] = e;
    s_cur[t] = e;
  }
  if (t == 0) s_off[BIN_NODES] = cnt;
  __syncthreads();

  for (int i = t; i < cnt; i += 512) {
    const uint2 r = bucket[rbase + i];
    const int d = r.x >> 17;
    const int p = atomicAdd(&s_cur[d], 1);
    s_src[p] = r.x & 0x1FFFFu;
    s_val[p] = f32_to_bf16_rne(__uint_as_float(r.y));
  }
  __syncthreads();

  // gather: wave per node (8 waves -> 8 nodes in flight, 16 rounds);
  // half-waves on even/odd records; 8 records/half in flight in main loop.
  const int lane = t & 63;
  const int wave = t >> 6;
  const int half = lane >> 5;
  const int hl = lane & 31;
  const int node0 = bin * BIN_NODES;
  float csx = 0.f, csy = 0.f, cs2x = 0.f, cs2y = 0.f;

  for (int nl = wave; nl < BIN_NODES; nl += 8) {
    const int node = node0 + nl;
    if (node < n_nodes) {
      const int jb = s_off[nl], je = s_off[nl + 1];
      float a0x = 0.f, a0y = 0.f, a1x = 0.f, a1y = 0.f;
      float a2x = 0.f, a2y = 0.f, a3x = 0.f, a3y = 0.f;
      float a4x = 0.f, a4y = 0.f, a5x = 0.f, a5y = 0.f;
      float a6x = 0.f, a6y = 0.f, a7x = 0.f, a7y = 0.f;
      int j = jb + half;
      // main: 16 records per wave-iteration, 8 loads in flight per half
      for (; j + 14 < je; j += 16) {
        const uint src0 = s_src[j],      src1 = s_src[j + 2];
        const uint src2 = s_src[j + 4],  src3 = s_src[j + 6];
        const uint src4 = s_src[j + 8],  src5 = s_src[j + 10];
        const uint src6 = s_src[j + 12], src7 = s_src[j + 14];
        const float v0 = bf16_to_f32(s_val[j]);
        const float v1 = bf16_to_f32(s_val[j + 2]);
        const float v2 = bf16_to_f32(s_val[j + 4]);
        const float v3 = bf16_to_f32(s_val[j + 6]);
        const float v4 = bf16_to_f32(s_val[j + 8]);
        const float v5 = bf16_to_f32(s_val[j + 10]);
        const float v6 = bf16_to_f32(s_val[j + 12]);
        const float v7 = bf16_to_f32(s_val[j + 14]);
        const uint p0 = *(const uint*)&pre16[(size_t)src0 * D_OUT + 2 * hl];
        const uint p1 = *(const uint*)&pre16[(size_t)src1 * D_OUT + 2 * hl];
        const uint p2 = *(const uint*)&pre16[(size_t)src2 * D_OUT + 2 * hl];
        const uint p3 = *(const uint*)&pre16[(size_t)src3 * D_OUT + 2 * hl];
        const uint p4 = *(const uint*)&pre16[(size_t)src4 * D_OUT + 2 * hl];
        const uint p5 = *(const uint*)&pre16[(size_t)src5 * D_OUT + 2 * hl];
        const uint p6 = *(const uint*)&pre16[(size_t)src6 * D_OUT + 2 * hl];
        const uint p7 = *(const uint*)&pre16[(size_t)src7 * D_OUT + 2 * hl];
        a0x += v0 * bf16_to_f32((ushort)(p0 & 0xFFFFu));
        a0y += v0 * bf16_to_f32((ushort)(p0 >> 16));
        a1x += v1 * bf16_to_f32((ushort)(p1 & 0xFFFFu));
        a1y += v1 * bf16_to_f32((ushort)(p1 >> 16));
        a2x += v2 * bf16_to_f32((ushort)(p2 & 0xFFFFu));
        a2y += v2 * bf16_to_f32((ushort)(p2 >> 16));
        a3x += v3 * bf16_to_f32((ushort)(p3 & 0xFFFFu));
        a3y += v3 * bf16_to_f32((ushort)(p3 >> 16));
        a4x += v4 * bf16_to_f32((ushort)(p4 & 0xFFFFu));
        a4y += v4 * bf16_to_f32((ushort)(p4 >> 16));
        a5x += v5 * bf16_to_f32((ushort)(p5 & 0xFFFFu));
        a5y += v5 * bf16_to_f32((ushort)(p5 >> 16));
        a6x += v6 * bf16_to_f32((ushort)(p6 & 0xFFFFu));
        a6y += v6 * bf16_to_f32((ushort)(p6 >> 16));
        a7x += v7 * bf16_to_f32((ushort)(p7 & 0xFFFFu));
        a7y += v7 * bf16_to_f32((ushort)(p7 >> 16));
      }
      // mid: 8 records per wave-iteration, 4 loads in flight per half
      for (; j + 6 < je; j += 8) {
        const uint src0 = s_src[j],     src1 = s_src[j + 2];
        const uint src2 = s_src[j + 4], src3 = s_src[j + 6];
        const float v0 = bf16_to_f32(s_val[j]);
        const float v1 = bf16_to_f32(s_val[j + 2]);
        const float v2 = bf16_to_f32(s_val[j + 4]);
        const float v3 = bf16_to_f32(s_val[j + 6]);
        const uint p0 = *(const uint*)&pre16[(size_t)src0 * D_OUT + 2 * hl];
        const uint p1 = *(const uint*)&pre16[(size_t)src1 * D_OUT + 2 * hl];
        const uint p2 = *(const uint*)&pre16[(size_t)src2 * D_OUT + 2 * hl];
        const uint p3 = *(const uint*)&pre16[(size_t)src3 * D_OUT + 2 * hl];
        a0x += v0 * bf16_to_f32((ushort)(p0 & 0xFFFFu));
        a0y += v0 * bf16_to_f32((ushort)(p0 >> 16));
        a1x += v1 * bf16_to_f32((ushort)(p1 & 0xFFFFu));
        a1y += v1 * bf16_to_f32((ushort)(p1 >> 16));
        a2x += v2 * bf16_to_f32((ushort)(p2 & 0xFFFFu));
        a2y += v2 * bf16_to_f32((ushort)(p2 >> 16));
        a3x += v3 * bf16_to_f32((ushort)(p3 & 0xFFFFu));
        a3y += v3 * bf16_to_f32((ushort)(p3 >> 16));
      }
      for (; j < je; j += 2) {
        const uint src = s_src[j];
        const float v = bf16_to_f32(s_val[j]);
        const uint p = *(const uint*)&pre16[(size_t)src * D_OUT + 2 * hl];
        a0x += v * bf16_to_f32((ushort)(p & 0xFFFFu));
        a0y += v * bf16_to_f32((ushort)(p >> 16));
      }
      float ax = ((a0x + a1x) + (a2x + a3x)) + ((a4x + a5x) + (a6x + a7x));
      float ay = ((a0y + a1y) + (a2y + a3y)) + ((a4y + a5y) + (a6y + a7y));
      ax += __shfl_xor(ax, 32);   // merge odd-record half into even half
      ay += __shfl_xor(ay, 32);
      if (half == 0) {
        *(float2*)&out[(size_t)node * D_OUT + 2 * hl] = make_float2(ax, ay);
        csx += ax;
        cs2x += ax * ax;
        csy += ay;
        cs2y += ay * ay;
      }
    }
  }
  __syncthreads();  // record reads done; alias reduction buffers onto s_src

  float* red = (float*)s_src;       // [8 waves][64 cols] sums (2 KB)
  float* red2 = red + 512;          // [8 waves][64 cols] sumsq (2 KB)
  if (half == 0) {
    red[wave * 64 + 2 * hl] = csx;
    red[wave * 64 + 2 * hl + 1] = csy;
    red2[wave * 64 + 2 * hl] = cs2x;
    red2[wave * 64 + 2 * hl + 1] = cs2y;
  }
  __syncthreads();
  if (t < 64) {
    float s = 0.f, s2 = 0.f;
#pragma unroll
    for (int wv = 0; wv < 8; ++wv) {
      s += red[wv * 64 + t];
      s2 += red2[wv * 64 + t];
    }
    atomicAdd(&stats[t], s);
    atomicAdd(&stats[64 + t], s2);
  }
}

// ---------------- Normalize + ReLU (in place, float4) ----------------
__global__ __launch_bounds__(256) void norm_kernel(
    float* __restrict__ out, const float* __restrict__ stats, int64_t n_vec4,
    float inv_n) {
  const int c = (threadIdx.x * 4) & 63;
  float mean[4], scale[4];
#pragma unroll
  for (int k = 0; k < 4; ++k) {
    mean[k] = stats[c + k] * inv_n;
    const float var = stats[64 + c + k] * inv_n - mean[k] * mean[k];
    scale[k] = rsqrtf(var + BN_EPS);
  }
  const int64_t stride = (int64_t)gridDim.x * 256;
  for (int64_t i = (int64_t)blockIdx.x * 256 + threadIdx.x; i < n_vec4;
       i += stride) {
    float4 v = ((float4*)out)[i];
    v.x = (v.x - mean[0]) * scale[0];
    v.y = (v.y - mean[1]) * scale[1];
    v.z = (v.z - mean[2]) * scale[2];
    v.w = (v.w - mean[3]) * scale[3];
    v.x = v.x > 0.f ? v.x : 0.f;
    v.y = v.y > 0.f ? v.y : 0.f;
    v.z = v.z > 0.f ? v.z : 0.f;
    v.w = v.w > 0.f ? v.w : 0.f;
    ((float4*)out)[i] = v;
  }
}

// ---------------- launch: 4 dispatches total ----------------
extern "C" void kernel_launch(void* const* d_in, const int* in_sizes, int n_in,
                              void* d_out, int out_size, void* d_ws,
                              size_t ws_size, hipStream_t stream) {
  const float* x = (const float*)d_in[0];
  const float* W = (const float*)d_in[1];
  const float* ev = (const float*)d_in[2];
  const int* esrc = (const int*)d_in[3];
  const int* edst = (const int*)d_in[4];

  const int n_nodes = in_sizes[0] / D_IN;
  const int n_edges = in_sizes[2];
  const int64_t n_out = (int64_t)n_nodes * D_OUT;
  const int n_bins = (n_nodes + BIN_NODES - 1) >> BIN_SHIFT;
  const int n_row_tiles = (n_nodes + 63) / 64;

  float* out = (float*)d_out;

  // workspace layout
  char* w = (char*)d_ws;
  ushort* pre16 = (ushort*)w;             w += (size_t)n_nodes * D_OUT * 2;
  int* bin_cursor = (int*)w;              w += (size_t)n_bins * 4;
  float* stats = (float*)w;               w += 128 * 4;
  w = (char*)(((uintptr_t)w + 7) & ~(uintptr_t)7);
  uint2* bucket = (uint2*)w;              // n_bins * BIN_CAP * 8 bytes (~32 MB)

  gemm_mfma_kernel<<<(n_row_tiles + 1) / 2, 256, 0, stream>>>(
      x, W, pre16, bin_cursor, stats, n_bins, n_nodes, n_row_tiles);
  partition_kernel<<<(n_edges + CHUNK - 1) / CHUNK, 256, 0, stream>>>(
      ev, esrc, edst, bin_cursor, bucket, n_edges, n_bins);
  bin_sort_gather_kernel<<<n_bins, 512, 0, stream>>>(pre16, bucket, bin_cursor,
                                                     out, stats, n_nodes);
  norm_kernel<<<2048, 256, 0, stream>>>(out, stats, n_out / 4,
                                        1.0f / (float)n_nodes);
}